// Round 18
// baseline (362.596 us; speedup 1.0000x reference)
//
#include <hip/hip_runtime.h>

// Round 18: T4 depth-1 counted-vmcnt pipeline on TERMS=1 GEMMs (QK, PV).
// Per K-step: STAGE(next buf) -> s_waitcnt vmcnt(8) (cur's loads done, next's
// 8 stay in flight) -> raw s_barrier -> COMPUTE(cur) -> lgkmcnt(0) -> barrier.
// LDS 64KB dbuf (2 blocks/CU = measured residency, no loss). proj (TERMS=2)
// keeps the single-buffer path. Everything else identical to R17 (354us).

typedef __attribute__((ext_vector_type(8))) _Float16 f16x8;
typedef __attribute__((ext_vector_type(4))) float f32x4;
typedef unsigned short u16;
typedef unsigned int u32;

#define B_ 8
#define SQL 2048
#define SKL 2048
#define DD 1024
#define NEGC -1000000000.0f

static __device__ __forceinline__ u16 f2h(float x) {
  _Float16 h = (_Float16)x;                       // v_cvt_f16_f32, RNE
  return __builtin_bit_cast(u16, h);
}
static __device__ __forceinline__ float h2f(u16 v) {
  return (float)__builtin_bit_cast(_Float16, v);
}
static __device__ __forceinline__ void gload16(const void* g, void* l) {
  __builtin_amdgcn_global_load_lds((const __attribute__((address_space(1))) u32*)g,
                                   (__attribute__((address_space(3))) u32*)l, 16, 0, 0);
}

// ---------------- convert fp32 -> fp16 (single) ----------------
__global__ __launch_bounds__(256) void cvt16_k(const float* __restrict__ in,
                                               u16* __restrict__ out, long n) {
  long i = ((long)blockIdx.x * 256 + threadIdx.x) * 8;
  long stride = (long)gridDim.x * 256 * 8;
  for (; i < n; i += stride) {
    float4 v0 = *(const float4*)(in + i);
    float4 v1 = *(const float4*)(in + i + 4);
    ushort4 o0 = make_ushort4(f2h(v0.x), f2h(v0.y), f2h(v0.z), f2h(v0.w));
    ushort4 o1 = make_ushort4(f2h(v1.x), f2h(v1.y), f2h(v1.z), f2h(v1.w));
    *(ushort4*)(out + i) = o0;
    *(ushort4*)(out + i + 4) = o1;
  }
}

// ---------------- split fp32 -> fp16 hi + fp16 lo (for W) ----------------
__global__ __launch_bounds__(256) void split16_k(const float* __restrict__ in,
                                                 u16* __restrict__ hi, u16* __restrict__ lo,
                                                 long n) {
  long i = ((long)blockIdx.x * 256 + threadIdx.x) * 4;
  long stride = (long)gridDim.x * 256 * 4;
  for (; i < n; i += stride) {
    float4 v = *(const float4*)(in + i);
    u16 h0 = f2h(v.x), h1 = f2h(v.y), h2 = f2h(v.z), h3 = f2h(v.w);
    *(ushort4*)(hi + i) = make_ushort4(h0, h1, h2, h3);
    *(ushort4*)(lo + i) = make_ushort4(f2h(v.x - h2f(h0)), f2h(v.y - h2f(h1)),
                                       f2h(v.z - h2f(h2)), f2h(v.w - h2f(h3)));
  }
}

// ---------------- fused mem: fp32 [Sk][D] -> memh fp16 + memT fp16 [D][Sk] ----------------
__global__ __launch_bounds__(256) void split_mem16_k(const float* __restrict__ in,
                                                     u16* __restrict__ hi,
                                                     u16* __restrict__ trn) {
  __shared__ u16 t[64][65];
  long bo = (long)blockIdx.z * SKL * DD;
  int r0 = blockIdx.y * 64, c0 = blockIdx.x * 64;
  int tr = threadIdx.x / 16, tc4 = (threadIdx.x % 16) * 4;
#pragma unroll
  for (int i = 0; i < 4; ++i) {
    int r = tr + i * 16;
    long idx = bo + (long)(r0 + r) * DD + c0 + tc4;
    float4 v = *(const float4*)(in + idx);
    u16 h0 = f2h(v.x), h1 = f2h(v.y), h2 = f2h(v.z), h3 = f2h(v.w);
    *(ushort4*)(hi + idx) = make_ushort4(h0, h1, h2, h3);
    t[r][tc4 + 0] = h0; t[r][tc4 + 1] = h1; t[r][tc4 + 2] = h2; t[r][tc4 + 3] = h3;
  }
  __syncthreads();
#pragma unroll
  for (int i = 0; i < 4; ++i) {
    int c = tr + i * 16;   // output row = original column c0+c
    ushort4 v = make_ushort4(t[tc4 + 0][c], t[tc4 + 1][c], t[tc4 + 2][c], t[tc4 + 3][c]);
    *(ushort4*)(trn + bo + (long)(c0 + c) * SKL + r0 + tc4) = v;
  }
}

// ---------------- unified B^T-layout fp16 MFMA GEMM ----------------
// C[m][n] = sum_k A[m][k]*B[n][k]; 128x128 tile, 4 waves (2x2), BK=64,
// mfma_f32_16x16x32_f16, XOR-swizzled LDS via pre-swizzled global source,
// T1 XCD-chunked tile swizzle.
// TERMS=2: single-buffer, B dual (Bh|Bl) 16-chunk 256B rows.     proj
// TERMS=1: DOUBLE-buffer + counted-vmcnt pipeline (T4 depth-1).  QK/PV
// OUTMODE: 0 = fp32 ; 1 = fp16 single
template <int TERMS, int OUTMODE, bool BIAS>
__global__ __launch_bounds__(256, 2) void gemm_f16(
    const u16* __restrict__ Ah,
    const u16* __restrict__ Bh, const u16* __restrict__ Bl,
    const float* __restrict__ bias,
    void* __restrict__ C0,
    int N, int K, long batchA, long batchB, long batchC) {
  constexpr int NBUF = (TERMS == 1) ? 2 : 1;
  constexpr int RWB = (TERMS == 2) ? 128 : 64;   // u16 per B LDS row
  __shared__ u16 lA[NBUF][128 * 64];
  __shared__ u16 lB[NBUF][128 * RWB];

  // ---- T1 XCD swizzle (bijective; nwg % 8 == 0 in all uses) ----
  const int nx = gridDim.x;
  int i0 = blockIdx.y * nx + blockIdx.x;
  int nwg = nx * gridDim.y;
  int j = (i0 & 7) * (nwg >> 3) + (i0 >> 3);
  const int bx = j % nx, by = j / nx;

  const int bz = blockIdx.z;
  const u16* pAh = Ah + (long)bz * batchA;
  const u16* pBh = Bh + (long)bz * batchB;
  const u16* pBl = (TERMS == 2) ? Bl : nullptr;   // proj W has no batch

  const int tid = threadIdx.x;
  const int l = tid & 63, w = tid >> 6;
  const int wr = w >> 1, wc = w & 1;
  const long am0 = (long)by * 128;
  const long bn0 = (long)bx * 128;

  f32x4 acc[4][4];
#pragma unroll
  for (int i = 0; i < 4; ++i)
#pragma unroll
    for (int j2 = 0; j2 < 4; ++j2) {
      f32x4 z = {0.f, 0.f, 0.f, 0.f};
      acc[i][j2] = z;
    }

  const int lrow = l & 15, lch = l >> 4;

  if constexpr (TERMS == 1) {
    // ---------- pipelined path (QK / PV) ----------
    auto STAGE = [&](int buf, int k0) {
#pragma unroll
      for (int i = 0; i < 4; ++i) {
        int row = i * 32 + (tid >> 3);
        int cc = (tid & 7) ^ (row & 7);
        gload16(pAh + (am0 + row) * K + k0 + cc * 8, &lA[buf][row * 64 + (tid & 7) * 8]);
        gload16(pBh + (bn0 + row) * K + k0 + cc * 8, &lB[buf][row * 64 + (tid & 7) * 8]);
      }
    };
    auto COMPUTE = [&](int buf) {
#pragma unroll
      for (int kk = 0; kk < 2; ++kk) {
        f16x8 ah[4], bh[4];
#pragma unroll
        for (int f = 0; f < 4; ++f) {
          int ra = wr * 64 + f * 16 + lrow;
          int rb = wc * 64 + f * 16 + lrow;
          int c = kk * 4 + lch;
          ah[f] = *(const f16x8*)&lA[buf][ra * 64 + (c ^ (ra & 7)) * 8];
          bh[f] = *(const f16x8*)&lB[buf][rb * 64 + (c ^ (rb & 7)) * 8];
        }
#pragma unroll
        for (int mf = 0; mf < 4; ++mf)
#pragma unroll
          for (int nf = 0; nf < 4; ++nf)
            acc[mf][nf] = __builtin_amdgcn_mfma_f32_16x16x32_f16(ah[mf], bh[nf], acc[mf][nf], 0, 0, 0);
      }
    };

    const int KITER = K >> 6;
    STAGE(0, 0);                 // prologue: 8 loads in flight
    int cur = 0;
    for (int t = 0; t < KITER; ++t) {
      if (t + 1 < KITER) {
        STAGE(cur ^ 1, (t + 1) << 6);                    // issue next (8 loads)
        asm volatile("s_waitcnt vmcnt(8)" ::: "memory"); // cur done, next in flight
      } else {
        asm volatile("s_waitcnt vmcnt(0)" ::: "memory"); // last tile: drain
      }
      __builtin_amdgcn_sched_barrier(0);
      __builtin_amdgcn_s_barrier();                      // cur tile visible to all
      __builtin_amdgcn_sched_barrier(0);
      COMPUTE(cur);
      asm volatile("s_waitcnt lgkmcnt(0)" ::: "memory"); // my LDS reads drained
      __builtin_amdgcn_sched_barrier(0);
      __builtin_amdgcn_s_barrier();                      // safe to overwrite cur next round
      cur ^= 1;
    }
  } else {
    // ---------- single-buffer path (proj, TERMS=2) ----------
    for (int k0 = 0; k0 < K; k0 += 64) {
      __syncthreads();
#pragma unroll
      for (int i = 0; i < 4; ++i) {
        int row = i * 32 + (tid >> 3);
        int cc = (tid & 7) ^ (row & 7);
        gload16(pAh + (am0 + row) * K + k0 + cc * 8, &lA[0][row * 64 + (tid & 7) * 8]);
      }
#pragma unroll
      for (int i = 0; i < 8; ++i) {
        int row = i * 16 + (tid >> 4);
        int s = tid & 15;
        int cc = s ^ (row & 15);
        const u16* src = (cc < 8) ? (pBh + (bn0 + row) * K + k0 + cc * 8)
                                  : (pBl + (bn0 + row) * K + k0 + (cc - 8) * 8);
        gload16(src, &lB[0][row * 128 + s * 8]);
      }
      __syncthreads();

#pragma unroll
      for (int kk = 0; kk < 2; ++kk) {
        f16x8 ah[4], bh[4], bl_[4];
#pragma unroll
        for (int f = 0; f < 4; ++f) {
          int ra = wr * 64 + f * 16 + lrow;
          int rb = wc * 64 + f * 16 + lrow;
          int c = kk * 4 + lch;
          ah[f] = *(const f16x8*)&lA[0][ra * 64 + (c ^ (ra & 7)) * 8];
          bh[f] = *(const f16x8*)&lB[0][rb * 128 + (c ^ (rb & 15)) * 8];
          bl_[f] = *(const f16x8*)&lB[0][rb * 128 + ((8 + c) ^ (rb & 15)) * 8];
        }
#pragma unroll
        for (int mf = 0; mf < 4; ++mf)
#pragma unroll
          for (int nf = 0; nf < 4; ++nf) {
            acc[mf][nf] = __builtin_amdgcn_mfma_f32_16x16x32_f16(ah[mf], bh[nf], acc[mf][nf], 0, 0, 0);
            acc[mf][nf] = __builtin_amdgcn_mfma_f32_16x16x32_f16(ah[mf], bl_[nf], acc[mf][nf], 0, 0, 0);
          }
      }
    }
  }

  // epilogue: C/D layout col = lane&15, row = (lane>>4)*4 + reg
#pragma unroll
  for (int mf = 0; mf < 4; ++mf)
#pragma unroll
    for (int nf = 0; nf < 4; ++nf)
#pragma unroll
      for (int r = 0; r < 4; ++r) {
        long row = am0 + wr * 64 + mf * 16 + (l >> 4) * 4 + r;
        long col = bn0 + wc * 64 + nf * 16 + (l & 15);
        float v = acc[mf][nf][r];
        if (BIAS) v += bias[col];
        long idx = (long)bz * batchC + row * N + col;
        if (OUTMODE == 0) ((float*)C0)[idx] = v;
        else              ((u16*)C0)[idx] = f2h(v);
      }
}

// ---------------- mask + row softmax: S fp32, mask int32 -> P fp16 ----------------
__global__ __launch_bounds__(256) void softmax16_k(const float* __restrict__ S,
                                                   const int* __restrict__ M,
                                                   u16* __restrict__ P) {
  long row = blockIdx.x;
  const float* s = S + row * SKL;
  const int* m = M + row * SKL;
  u16* p = P + row * SKL;
  int t = threadIdx.x;
  float x[8];
#pragma unroll
  for (int j = 0; j < 2; ++j) {
    float4 v = *(const float4*)(s + t * 8 + j * 4);
    int4 q = *(const int4*)(m + t * 8 + j * 4);
    x[j * 4 + 0] = q.x ? v.x : v.x + NEGC;
    x[j * 4 + 1] = q.y ? v.y : v.y + NEGC;
    x[j * 4 + 2] = q.z ? v.z : v.z + NEGC;
    x[j * 4 + 3] = q.w ? v.w : v.w + NEGC;
  }
  float mx = x[0];
#pragma unroll
  for (int j = 1; j < 8; ++j) mx = fmaxf(mx, x[j]);
#pragma unroll
  for (int o = 32; o >= 1; o >>= 1) mx = fmaxf(mx, __shfl_xor(mx, o, 64));
  __shared__ float red[8];
  if ((t & 63) == 0) red[t >> 6] = mx;
  __syncthreads();
  mx = fmaxf(fmaxf(red[0], red[1]), fmaxf(red[2], red[3]));
  float e[8], sum = 0.f;
#pragma unroll
  for (int j = 0; j < 8; ++j) { e[j] = __expf(x[j] - mx); sum += e[j]; }
#pragma unroll
  for (int o = 32; o >= 1; o >>= 1) sum += __shfl_xor(sum, o, 64);
  if ((t & 63) == 0) red[4 + (t >> 6)] = sum;
  __syncthreads();
  float inv = 1.f / (red[4] + red[5] + red[6] + red[7]);
  ushort4 o0 = make_ushort4(f2h(e[0] * inv), f2h(e[1] * inv), f2h(e[2] * inv), f2h(e[3] * inv));
  ushort4 o1 = make_ushort4(f2h(e[4] * inv), f2h(e[5] * inv), f2h(e[6] * inv), f2h(e[7] * inv));
  *(ushort4*)(p + t * 8) = o0;
  *(ushort4*)(p + t * 8 + 4) = o1;
}

extern "C" void kernel_launch(void* const* d_in, const int* in_sizes, int n_in,
                              void* d_out, int out_size, void* d_ws, size_t ws_size,
                              hipStream_t stream) {
  const float* query = (const float*)d_in[0];
  const float* mem = (const float*)d_in[1];
  const int* mask = (const int*)d_in[2];
  const float* Wm = (const float*)d_in[3];
  const float* bias = (const float*)d_in[4];
  float* out = (float*)d_out;   // fp32 output

  const long nQ = (long)B_ * SQL * DD;   // 16.7M
  const long nW = (long)DD * DD;
  const long nS = (long)B_ * SQL * SKL;

  char* ws = (char*)d_ws;
  u16* q16 = (u16*)ws; ws += nQ * 2;    // fp16(query); becomes P after proj+QK
  u16* memh = (u16*)ws; ws += nQ * 2;
  u16* memT = (u16*)ws; ws += nQ * 2;
  u16* q1 = (u16*)ws; ws += nQ * 2;     // projected q, fp16
  u16* wh = (u16*)ws; ws += nW * 2;
  u16* wl = (u16*)ws; ws += nW * 2;
  float* S = (float*)ws; ws += nS * 4;
  u16* P = q16;   // q16 dead after projection

  cvt16_k<<<2048, 256, 0, stream>>>(query, q16, nQ);
  split16_k<<<512, 256, 0, stream>>>(Wm, wh, wl, nW);
  split_mem16_k<<<dim3(DD / 64, SKL / 64, B_), 256, 0, stream>>>(mem, memh, memT);

  // projection (2-term): M=16384, N=D, K=D ; q -> fp16
  gemm_f16<2, 1, true><<<dim3(DD / 128, (B_ * SQL) / 128, 1), 256, 0, stream>>>(
      q16, wh, wl, bias, q1, DD, DD, 0, 0, 0);
  // logits (1-term, pipelined): per batch M=Sq, N=Sk, K=D ; fp32 S
  gemm_f16<1, 0, false><<<dim3(SKL / 128, SQL / 128, B_), 256, 0, stream>>>(
      q1, memh, nullptr, nullptr, S, SKL, DD,
      (long)SQL * DD, (long)SKL * DD, (long)SQL * SKL);
  // mask + softmax -> P fp16
  softmax16_k<<<B_ * SQL, 256, 0, stream>>>(S, mask, P);
  // PV (1-term, pipelined): per batch M=Sq, N=D, K=Sk ; B = memT ; fp32 out
  gemm_f16<1, 0, false><<<dim3(DD / 128, SQL / 128, B_), 256, 0, stream>>>(
      P, memT, nullptr, nullptr, out, DD, SKL,
      (long)SQL * SKL, (long)DD * SKL, (long)SQL * DD);
}

// Round 19
// 326.177 us; speedup vs baseline: 1.1117x; 1.1117x over previous
//
#include <hip/hip_runtime.h>

// Round 19: revert R18 pipeline (neutral: occupancy loss ate the overlap).
// Change vs R17: TERMS=1 GEMMs (QK, PV) use a 256x128 tile -- 64 MFMA per
// K-step vs 32 against the same staging+barrier cost (MfmaUtil 24% -> ~35%).
// acc[8][4] = 128 VGPR, LDS 48KB. proj/softmax/prep identical to R17 (354us).

typedef __attribute__((ext_vector_type(8))) _Float16 f16x8;
typedef __attribute__((ext_vector_type(4))) float f32x4;
typedef unsigned short u16;
typedef unsigned int u32;

#define B_ 8
#define SQL 2048
#define SKL 2048
#define DD 1024
#define NEGC -1000000000.0f

static __device__ __forceinline__ u16 f2h(float x) {
  _Float16 h = (_Float16)x;                       // v_cvt_f16_f32, RNE
  return __builtin_bit_cast(u16, h);
}
static __device__ __forceinline__ float h2f(u16 v) {
  return (float)__builtin_bit_cast(_Float16, v);
}
static __device__ __forceinline__ void gload16(const void* g, void* l) {
  __builtin_amdgcn_global_load_lds((const __attribute__((address_space(1))) u32*)g,
                                   (__attribute__((address_space(3))) u32*)l, 16, 0, 0);
}

// ---------------- convert fp32 -> fp16 (single) ----------------
__global__ __launch_bounds__(256) void cvt16_k(const float* __restrict__ in,
                                               u16* __restrict__ out, long n) {
  long i = ((long)blockIdx.x * 256 + threadIdx.x) * 8;
  long stride = (long)gridDim.x * 256 * 8;
  for (; i < n; i += stride) {
    float4 v0 = *(const float4*)(in + i);
    float4 v1 = *(const float4*)(in + i + 4);
    ushort4 o0 = make_ushort4(f2h(v0.x), f2h(v0.y), f2h(v0.z), f2h(v0.w));
    ushort4 o1 = make_ushort4(f2h(v1.x), f2h(v1.y), f2h(v1.z), f2h(v1.w));
    *(ushort4*)(out + i) = o0;
    *(ushort4*)(out + i + 4) = o1;
  }
}

// ---------------- split fp32 -> fp16 hi + fp16 lo (for W) ----------------
__global__ __launch_bounds__(256) void split16_k(const float* __restrict__ in,
                                                 u16* __restrict__ hi, u16* __restrict__ lo,
                                                 long n) {
  long i = ((long)blockIdx.x * 256 + threadIdx.x) * 4;
  long stride = (long)gridDim.x * 256 * 4;
  for (; i < n; i += stride) {
    float4 v = *(const float4*)(in + i);
    u16 h0 = f2h(v.x), h1 = f2h(v.y), h2 = f2h(v.z), h3 = f2h(v.w);
    *(ushort4*)(hi + i) = make_ushort4(h0, h1, h2, h3);
    *(ushort4*)(lo + i) = make_ushort4(f2h(v.x - h2f(h0)), f2h(v.y - h2f(h1)),
                                       f2h(v.z - h2f(h2)), f2h(v.w - h2f(h3)));
  }
}

// ---------------- fused mem: fp32 [Sk][D] -> memh fp16 + memT fp16 [D][Sk] ----------------
__global__ __launch_bounds__(256) void split_mem16_k(const float* __restrict__ in,
                                                     u16* __restrict__ hi,
                                                     u16* __restrict__ trn) {
  __shared__ u16 t[64][65];
  long bo = (long)blockIdx.z * SKL * DD;
  int r0 = blockIdx.y * 64, c0 = blockIdx.x * 64;
  int tr = threadIdx.x / 16, tc4 = (threadIdx.x % 16) * 4;
#pragma unroll
  for (int i = 0; i < 4; ++i) {
    int r = tr + i * 16;
    long idx = bo + (long)(r0 + r) * DD + c0 + tc4;
    float4 v = *(const float4*)(in + idx);
    u16 h0 = f2h(v.x), h1 = f2h(v.y), h2 = f2h(v.z), h3 = f2h(v.w);
    *(ushort4*)(hi + idx) = make_ushort4(h0, h1, h2, h3);
    t[r][tc4 + 0] = h0; t[r][tc4 + 1] = h1; t[r][tc4 + 2] = h2; t[r][tc4 + 3] = h3;
  }
  __syncthreads();
#pragma unroll
  for (int i = 0; i < 4; ++i) {
    int c = tr + i * 16;   // output row = original column c0+c
    ushort4 v = make_ushort4(t[tc4 + 0][c], t[tc4 + 1][c], t[tc4 + 2][c], t[tc4 + 3][c]);
    *(ushort4*)(trn + bo + (long)(c0 + c) * SKL + r0 + tc4) = v;
  }
}

// ---------------- unified B^T-layout fp16 MFMA GEMM ----------------
// C[m][n] = sum_k A[m][k]*B[n][k]; 4 waves (2x2), BK=64, single-buffer LDS,
// mfma_f32_16x16x32_f16, XOR-swizzled via pre-swizzled global source,
// T1 XCD-chunked tile swizzle.
// TERMS=2: 128x128 tile, B dual (Bh|Bl) 16-chunk 256B rows.   proj
// TERMS=1: 256x128 tile (MF=8), B single 8-chunk rows.        QK/PV
// OUTMODE: 0 = fp32 ; 1 = fp16 single
template <int TERMS, int OUTMODE, bool BIAS>
__global__ __launch_bounds__(256, 2) void gemm_f16(
    const u16* __restrict__ Ah,
    const u16* __restrict__ Bh, const u16* __restrict__ Bl,
    const float* __restrict__ bias,
    void* __restrict__ C0,
    int N, int K, long batchA, long batchB, long batchC) {
  constexpr int BM = (TERMS == 1) ? 256 : 128;   // M tile
  constexpr int MF = BM / 128 * 4;               // M fragments per wave (4 or 8)
  constexpr int RWB = (TERMS == 2) ? 128 : 64;   // u16 per B LDS row
  __shared__ u16 lA[BM * 64];
  __shared__ u16 lB[128 * RWB];

  // ---- T1 XCD swizzle (bijective; nwg % 8 == 0 in all uses) ----
  const int nx = gridDim.x;
  int i0 = blockIdx.y * nx + blockIdx.x;
  int nwg = nx * gridDim.y;
  int j = (i0 & 7) * (nwg >> 3) + (i0 >> 3);
  const int bx = j % nx, by = j / nx;

  const int bz = blockIdx.z;
  const u16* pAh = Ah + (long)bz * batchA;
  const u16* pBh = Bh + (long)bz * batchB;
  const u16* pBl = (TERMS == 2) ? Bl : nullptr;   // proj W has no batch

  const int tid = threadIdx.x;
  const int l = tid & 63, w = tid >> 6;
  const int wr = w >> 1, wc = w & 1;
  const long am0 = (long)by * BM;
  const long bn0 = (long)bx * 128;

  f32x4 acc[MF][4];
#pragma unroll
  for (int i = 0; i < MF; ++i)
#pragma unroll
    for (int j2 = 0; j2 < 4; ++j2) {
      f32x4 z = {0.f, 0.f, 0.f, 0.f};
      acc[i][j2] = z;
    }

  const int lrow = l & 15, lch = l >> 4;

  for (int k0 = 0; k0 < K; k0 += 64) {
    __syncthreads();
    // ---- A stage: single fp16, 8 chunks/row (proven involution) ----
#pragma unroll
    for (int i = 0; i < BM / 32; ++i) {
      int row = i * 32 + (tid >> 3);
      int cc = (tid & 7) ^ (row & 7);
      gload16(pAh + (am0 + row) * K + k0 + cc * 8, &lA[row * 64 + (tid & 7) * 8]);
    }
    // ---- B stage ----
    if (TERMS == 2) {
#pragma unroll
      for (int i = 0; i < 8; ++i) {
        int row = i * 16 + (tid >> 4);
        int s = tid & 15;
        int cc = s ^ (row & 15);
        const u16* src = (cc < 8) ? (pBh + (bn0 + row) * K + k0 + cc * 8)
                                  : (pBl + (bn0 + row) * K + k0 + (cc - 8) * 8);
        gload16(src, &lB[row * 128 + s * 8]);
      }
    } else {
#pragma unroll
      for (int i = 0; i < 4; ++i) {
        int row = i * 32 + (tid >> 3);
        int cc = (tid & 7) ^ (row & 7);
        gload16(pBh + (bn0 + row) * K + k0 + cc * 8, &lB[row * 64 + (tid & 7) * 8]);
      }
    }
    __syncthreads();

#pragma unroll
    for (int kk = 0; kk < 2; ++kk) {
      if (TERMS == 2) {
        f16x8 ah[4], bh[4], bl_[4];
#pragma unroll
        for (int f = 0; f < 4; ++f) {
          int ra = wr * 64 + f * 16 + lrow;
          int rb = wc * 64 + f * 16 + lrow;
          int c = kk * 4 + lch;
          ah[f] = *(const f16x8*)&lA[ra * 64 + (c ^ (ra & 7)) * 8];
          bh[f] = *(const f16x8*)&lB[rb * 128 + (c ^ (rb & 15)) * 8];
          bl_[f] = *(const f16x8*)&lB[rb * 128 + ((8 + c) ^ (rb & 15)) * 8];
        }
#pragma unroll
        for (int mf = 0; mf < 4; ++mf)
#pragma unroll
          for (int nf = 0; nf < 4; ++nf) {
            acc[mf][nf] = __builtin_amdgcn_mfma_f32_16x16x32_f16(ah[mf], bh[nf], acc[mf][nf], 0, 0, 0);
            acc[mf][nf] = __builtin_amdgcn_mfma_f32_16x16x32_f16(ah[mf], bl_[nf], acc[mf][nf], 0, 0, 0);
          }
      } else {
        f16x8 ah[8], bh[4];
#pragma unroll
        for (int f = 0; f < 8; ++f) {
          int ra = wr * 128 + f * 16 + lrow;   // wave covers 128 rows of 256
          int c = kk * 4 + lch;
          ah[f] = *(const f16x8*)&lA[ra * 64 + (c ^ (ra & 7)) * 8];
        }
#pragma unroll
        for (int f = 0; f < 4; ++f) {
          int rb = wc * 64 + f * 16 + lrow;
          int c = kk * 4 + lch;
          bh[f] = *(const f16x8*)&lB[rb * 64 + (c ^ (rb & 7)) * 8];
        }
#pragma unroll
        for (int mf = 0; mf < 8; ++mf)
#pragma unroll
          for (int nf = 0; nf < 4; ++nf)
            acc[mf][nf] = __builtin_amdgcn_mfma_f32_16x16x32_f16(ah[mf], bh[nf], acc[mf][nf], 0, 0, 0);
      }
    }
  }

  // epilogue: C/D layout col = lane&15, row = (lane>>4)*4 + reg
#pragma unroll
  for (int mf = 0; mf < MF; ++mf)
#pragma unroll
    for (int nf = 0; nf < 4; ++nf)
#pragma unroll
      for (int r = 0; r < 4; ++r) {
        long row = am0 + wr * (BM / 2) + mf * 16 + (l >> 4) * 4 + r;
        long col = bn0 + wc * 64 + nf * 16 + (l & 15);
        float v = acc[mf][nf][r];
        if (BIAS) v += bias[col];
        long idx = (long)bz * batchC + row * N + col;
        if (OUTMODE == 0) ((float*)C0)[idx] = v;
        else              ((u16*)C0)[idx] = f2h(v);
      }
}

// ---------------- mask + row softmax: S fp32, mask int32 -> P fp16 ----------------
__global__ __launch_bounds__(256) void softmax16_k(const float* __restrict__ S,
                                                   const int* __restrict__ M,
                                                   u16* __restrict__ P) {
  long row = blockIdx.x;
  const float* s = S + row * SKL;
  const int* m = M + row * SKL;
  u16* p = P + row * SKL;
  int t = threadIdx.x;
  float x[8];
#pragma unroll
  for (int j = 0; j < 2; ++j) {
    float4 v = *(const float4*)(s + t * 8 + j * 4);
    int4 q = *(const int4*)(m + t * 8 + j * 4);
    x[j * 4 + 0] = q.x ? v.x : v.x + NEGC;
    x[j * 4 + 1] = q.y ? v.y : v.y + NEGC;
    x[j * 4 + 2] = q.z ? v.z : v.z + NEGC;
    x[j * 4 + 3] = q.w ? v.w : v.w + NEGC;
  }
  float mx = x[0];
#pragma unroll
  for (int j = 1; j < 8; ++j) mx = fmaxf(mx, x[j]);
#pragma unroll
  for (int o = 32; o >= 1; o >>= 1) mx = fmaxf(mx, __shfl_xor(mx, o, 64));
  __shared__ float red[8];
  if ((t & 63) == 0) red[t >> 6] = mx;
  __syncthreads();
  mx = fmaxf(fmaxf(red[0], red[1]), fmaxf(red[2], red[3]));
  float e[8], sum = 0.f;
#pragma unroll
  for (int j = 0; j < 8; ++j) { e[j] = __expf(x[j] - mx); sum += e[j]; }
#pragma unroll
  for (int o = 32; o >= 1; o >>= 1) sum += __shfl_xor(sum, o, 64);
  if ((t & 63) == 0) red[4 + (t >> 6)] = sum;
  __syncthreads();
  float inv = 1.f / (red[4] + red[5] + red[6] + red[7]);
  ushort4 o0 = make_ushort4(f2h(e[0] * inv), f2h(e[1] * inv), f2h(e[2] * inv), f2h(e[3] * inv));
  ushort4 o1 = make_ushort4(f2h(e[4] * inv), f2h(e[5] * inv), f2h(e[6] * inv), f2h(e[7] * inv));
  *(ushort4*)(p + t * 8) = o0;
  *(ushort4*)(p + t * 8 + 4) = o1;
}

extern "C" void kernel_launch(void* const* d_in, const int* in_sizes, int n_in,
                              void* d_out, int out_size, void* d_ws, size_t ws_size,
                              hipStream_t stream) {
  const float* query = (const float*)d_in[0];
  const float* mem = (const float*)d_in[1];
  const int* mask = (const int*)d_in[2];
  const float* Wm = (const float*)d_in[3];
  const float* bias = (const float*)d_in[4];
  float* out = (float*)d_out;   // fp32 output

  const long nQ = (long)B_ * SQL * DD;   // 16.7M
  const long nW = (long)DD * DD;
  const long nS = (long)B_ * SQL * SKL;

  char* ws = (char*)d_ws;
  u16* q16 = (u16*)ws; ws += nQ * 2;    // fp16(query); becomes P after proj+QK
  u16* memh = (u16*)ws; ws += nQ * 2;
  u16* memT = (u16*)ws; ws += nQ * 2;
  u16* q1 = (u16*)ws; ws += nQ * 2;     // projected q, fp16
  u16* wh = (u16*)ws; ws += nW * 2;
  u16* wl = (u16*)ws; ws += nW * 2;
  float* S = (float*)ws; ws += nS * 4;
  u16* P = q16;   // q16 dead after projection

  cvt16_k<<<2048, 256, 0, stream>>>(query, q16, nQ);
  split16_k<<<512, 256, 0, stream>>>(Wm, wh, wl, nW);
  split_mem16_k<<<dim3(DD / 64, SKL / 64, B_), 256, 0, stream>>>(mem, memh, memT);

  // projection (2-term, 128x128): M=16384, N=D, K=D ; q -> fp16
  gemm_f16<2, 1, true><<<dim3(DD / 128, (B_ * SQL) / 128, 1), 256, 0, stream>>>(
      q16, wh, wl, bias, q1, DD, DD, 0, 0, 0);
  // logits (1-term, 256x128): per batch M=Sq, N=Sk, K=D ; fp32 S
  gemm_f16<1, 0, false><<<dim3(SKL / 128, SQL / 256, B_), 256, 0, stream>>>(
      q1, memh, nullptr, nullptr, S, SKL, DD,
      (long)SQL * DD, (long)SKL * DD, (long)SQL * SKL);
  // mask + softmax -> P fp16
  softmax16_k<<<B_ * SQL, 256, 0, stream>>>(S, mask, P);
  // PV (1-term, 256x128): per batch M=Sq, N=D, K=Sk ; B = memT ; fp32 out
  gemm_f16<1, 0, false><<<dim3(DD / 128, SQL / 256, B_), 256, 0, stream>>>(
      P, memT, nullptr, nullptr, out, DD, SKL,
      (long)SQL * SKL, (long)DD * SKL, (long)SQL * DD);
}

// Round 20
// 321.583 us; speedup vs baseline: 1.1275x; 1.0143x over previous
//
#include <hip/hip_runtime.h>

// Round 20: (a) proj joins the 256-row tile (TERMS=2, BM=256: 128 MFMA/K-step
// vs 16 staged loads/thread -- same lever as R19's QK/PV win). (b) softmax
// rewritten wave-per-row (4 waves/block, 64 lanes x 32 elems, shfl-only
// reduction, no barriers/LDS; was 4.6 TB/s block-per-row). QK/PV/prep = R19.

typedef __attribute__((ext_vector_type(8))) _Float16 f16x8;
typedef __attribute__((ext_vector_type(4))) float f32x4;
typedef unsigned short u16;
typedef unsigned int u32;

#define B_ 8
#define SQL 2048
#define SKL 2048
#define DD 1024
#define NEGC -1000000000.0f

static __device__ __forceinline__ u16 f2h(float x) {
  _Float16 h = (_Float16)x;                       // v_cvt_f16_f32, RNE
  return __builtin_bit_cast(u16, h);
}
static __device__ __forceinline__ float h2f(u16 v) {
  return (float)__builtin_bit_cast(_Float16, v);
}
static __device__ __forceinline__ void gload16(const void* g, void* l) {
  __builtin_amdgcn_global_load_lds((const __attribute__((address_space(1))) u32*)g,
                                   (__attribute__((address_space(3))) u32*)l, 16, 0, 0);
}

// ---------------- convert fp32 -> fp16 (single) ----------------
__global__ __launch_bounds__(256) void cvt16_k(const float* __restrict__ in,
                                               u16* __restrict__ out, long n) {
  long i = ((long)blockIdx.x * 256 + threadIdx.x) * 8;
  long stride = (long)gridDim.x * 256 * 8;
  for (; i < n; i += stride) {
    float4 v0 = *(const float4*)(in + i);
    float4 v1 = *(const float4*)(in + i + 4);
    ushort4 o0 = make_ushort4(f2h(v0.x), f2h(v0.y), f2h(v0.z), f2h(v0.w));
    ushort4 o1 = make_ushort4(f2h(v1.x), f2h(v1.y), f2h(v1.z), f2h(v1.w));
    *(ushort4*)(out + i) = o0;
    *(ushort4*)(out + i + 4) = o1;
  }
}

// ---------------- split fp32 -> fp16 hi + fp16 lo (for W) ----------------
__global__ __launch_bounds__(256) void split16_k(const float* __restrict__ in,
                                                 u16* __restrict__ hi, u16* __restrict__ lo,
                                                 long n) {
  long i = ((long)blockIdx.x * 256 + threadIdx.x) * 4;
  long stride = (long)gridDim.x * 256 * 4;
  for (; i < n; i += stride) {
    float4 v = *(const float4*)(in + i);
    u16 h0 = f2h(v.x), h1 = f2h(v.y), h2 = f2h(v.z), h3 = f2h(v.w);
    *(ushort4*)(hi + i) = make_ushort4(h0, h1, h2, h3);
    *(ushort4*)(lo + i) = make_ushort4(f2h(v.x - h2f(h0)), f2h(v.y - h2f(h1)),
                                       f2h(v.z - h2f(h2)), f2h(v.w - h2f(h3)));
  }
}

// ---------------- fused mem: fp32 [Sk][D] -> memh fp16 + memT fp16 [D][Sk] ----------------
__global__ __launch_bounds__(256) void split_mem16_k(const float* __restrict__ in,
                                                     u16* __restrict__ hi,
                                                     u16* __restrict__ trn) {
  __shared__ u16 t[64][65];
  long bo = (long)blockIdx.z * SKL * DD;
  int r0 = blockIdx.y * 64, c0 = blockIdx.x * 64;
  int tr = threadIdx.x / 16, tc4 = (threadIdx.x % 16) * 4;
#pragma unroll
  for (int i = 0; i < 4; ++i) {
    int r = tr + i * 16;
    long idx = bo + (long)(r0 + r) * DD + c0 + tc4;
    float4 v = *(const float4*)(in + idx);
    u16 h0 = f2h(v.x), h1 = f2h(v.y), h2 = f2h(v.z), h3 = f2h(v.w);
    *(ushort4*)(hi + idx) = make_ushort4(h0, h1, h2, h3);
    t[r][tc4 + 0] = h0; t[r][tc4 + 1] = h1; t[r][tc4 + 2] = h2; t[r][tc4 + 3] = h3;
  }
  __syncthreads();
#pragma unroll
  for (int i = 0; i < 4; ++i) {
    int c = tr + i * 16;   // output row = original column c0+c
    ushort4 v = make_ushort4(t[tc4 + 0][c], t[tc4 + 1][c], t[tc4 + 2][c], t[tc4 + 3][c]);
    *(ushort4*)(trn + bo + (long)(c0 + c) * SKL + r0 + tc4) = v;
  }
}

// ---------------- unified B^T-layout fp16 MFMA GEMM ----------------
// C[m][n] = sum_k A[m][k]*B[n][k]; 256x128 tile, 4 waves (2x2), BK=64,
// single-buffer LDS, mfma_f32_16x16x32_f16, XOR-swizzled via pre-swizzled
// global source, T1 XCD-chunked tile swizzle.
// TERMS=2: B dual (Bh|Bl) 16-chunk 256B rows, 128 MFMA/K-step.  proj
// TERMS=1: B single 8-chunk rows, 64 MFMA/K-step.               QK/PV
// OUTMODE: 0 = fp32 ; 1 = fp16 single
template <int TERMS, int OUTMODE, bool BIAS>
__global__ __launch_bounds__(256, 2) void gemm_f16(
    const u16* __restrict__ Ah,
    const u16* __restrict__ Bh, const u16* __restrict__ Bl,
    const float* __restrict__ bias,
    void* __restrict__ C0,
    int N, int K, long batchA, long batchB, long batchC) {
  constexpr int BM = 256;
  constexpr int MF = 8;                          // M fragments per wave
  constexpr int RWB = (TERMS == 2) ? 128 : 64;   // u16 per B LDS row
  __shared__ u16 lA[BM * 64];
  __shared__ u16 lB[128 * RWB];

  // ---- T1 XCD swizzle (bijective; nwg % 8 == 0 in all uses) ----
  const int nx = gridDim.x;
  int i0 = blockIdx.y * nx + blockIdx.x;
  int nwg = nx * gridDim.y;
  int j = (i0 & 7) * (nwg >> 3) + (i0 >> 3);
  const int bx = j % nx, by = j / nx;

  const int bz = blockIdx.z;
  const u16* pAh = Ah + (long)bz * batchA;
  const u16* pBh = Bh + (long)bz * batchB;
  const u16* pBl = (TERMS == 2) ? Bl : nullptr;   // proj W has no batch

  const int tid = threadIdx.x;
  const int l = tid & 63, w = tid >> 6;
  const int wr = w >> 1, wc = w & 1;
  const long am0 = (long)by * BM;
  const long bn0 = (long)bx * 128;

  f32x4 acc[MF][4];
#pragma unroll
  for (int i = 0; i < MF; ++i)
#pragma unroll
    for (int j2 = 0; j2 < 4; ++j2) {
      f32x4 z = {0.f, 0.f, 0.f, 0.f};
      acc[i][j2] = z;
    }

  const int lrow = l & 15, lch = l >> 4;

  for (int k0 = 0; k0 < K; k0 += 64) {
    __syncthreads();
    // ---- A stage: single fp16, 8 chunks/row (proven involution) ----
#pragma unroll
    for (int i = 0; i < BM / 32; ++i) {
      int row = i * 32 + (tid >> 3);
      int cc = (tid & 7) ^ (row & 7);
      gload16(pAh + (am0 + row) * K + k0 + cc * 8, &lA[row * 64 + (tid & 7) * 8]);
    }
    // ---- B stage ----
    if (TERMS == 2) {
#pragma unroll
      for (int i = 0; i < 8; ++i) {
        int row = i * 16 + (tid >> 4);
        int s = tid & 15;
        int cc = s ^ (row & 15);
        const u16* src = (cc < 8) ? (pBh + (bn0 + row) * K + k0 + cc * 8)
                                  : (pBl + (bn0 + row) * K + k0 + (cc - 8) * 8);
        gload16(src, &lB[row * 128 + s * 8]);
      }
    } else {
#pragma unroll
      for (int i = 0; i < 4; ++i) {
        int row = i * 32 + (tid >> 3);
        int cc = (tid & 7) ^ (row & 7);
        gload16(pBh + (bn0 + row) * K + k0 + cc * 8, &lB[row * 64 + (tid & 7) * 8]);
      }
    }
    __syncthreads();

#pragma unroll
    for (int kk = 0; kk < 2; ++kk) {
      if (TERMS == 2) {
        f16x8 ah[8], bh[4], bl_[4];
#pragma unroll
        for (int f = 0; f < 8; ++f) {
          int ra = wr * 128 + f * 16 + lrow;
          int c = kk * 4 + lch;
          ah[f] = *(const f16x8*)&lA[ra * 64 + (c ^ (ra & 7)) * 8];
        }
#pragma unroll
        for (int f = 0; f < 4; ++f) {
          int rb = wc * 64 + f * 16 + lrow;
          int c = kk * 4 + lch;
          bh[f] = *(const f16x8*)&lB[rb * 128 + (c ^ (rb & 15)) * 8];
          bl_[f] = *(const f16x8*)&lB[rb * 128 + ((8 + c) ^ (rb & 15)) * 8];
        }
#pragma unroll
        for (int mf = 0; mf < 8; ++mf)
#pragma unroll
          for (int nf = 0; nf < 4; ++nf) {
            acc[mf][nf] = __builtin_amdgcn_mfma_f32_16x16x32_f16(ah[mf], bh[nf], acc[mf][nf], 0, 0, 0);
            acc[mf][nf] = __builtin_amdgcn_mfma_f32_16x16x32_f16(ah[mf], bl_[nf], acc[mf][nf], 0, 0, 0);
          }
      } else {
        f16x8 ah[8], bh[4];
#pragma unroll
        for (int f = 0; f < 8; ++f) {
          int ra = wr * 128 + f * 16 + lrow;
          int c = kk * 4 + lch;
          ah[f] = *(const f16x8*)&lA[ra * 64 + (c ^ (ra & 7)) * 8];
        }
#pragma unroll
        for (int f = 0; f < 4; ++f) {
          int rb = wc * 64 + f * 16 + lrow;
          int c = kk * 4 + lch;
          bh[f] = *(const f16x8*)&lB[rb * 64 + (c ^ (rb & 7)) * 8];
        }
#pragma unroll
        for (int mf = 0; mf < 8; ++mf)
#pragma unroll
          for (int nf = 0; nf < 4; ++nf)
            acc[mf][nf] = __builtin_amdgcn_mfma_f32_16x16x32_f16(ah[mf], bh[nf], acc[mf][nf], 0, 0, 0);
      }
    }
  }

  // epilogue: C/D layout col = lane&15, row = (lane>>4)*4 + reg
#pragma unroll
  for (int mf = 0; mf < MF; ++mf)
#pragma unroll
    for (int nf = 0; nf < 4; ++nf)
#pragma unroll
      for (int r = 0; r < 4; ++r) {
        long row = am0 + wr * (BM / 2) + mf * 16 + (l >> 4) * 4 + r;
        long col = bn0 + wc * 64 + nf * 16 + (l & 15);
        float v = acc[mf][nf][r];
        if (BIAS) v += bias[col];
        long idx = (long)bz * batchC + row * N + col;
        if (OUTMODE == 0) ((float*)C0)[idx] = v;
        else              ((u16*)C0)[idx] = f2h(v);
      }
}

// ---------------- mask + row softmax, wave-per-row (no barriers/LDS) ----------------
// 4 waves/block, each owns one row: 64 lanes x 32 elems (8 float4 loads).
__global__ __launch_bounds__(256) void softmax16_k(const float* __restrict__ S,
                                                   const int* __restrict__ M,
                                                   u16* __restrict__ P) {
  long row = (long)blockIdx.x * 4 + (threadIdx.x >> 6);
  const float* s = S + row * SKL;
  const int* m = M + row * SKL;
  u16* p = P + row * SKL;
  const int lane = threadIdx.x & 63;
  float x[32];
#pragma unroll
  for (int j = 0; j < 8; ++j) {
    float4 v = *(const float4*)(s + lane * 4 + j * 256);
    int4 q = *(const int4*)(m + lane * 4 + j * 256);
    x[j * 4 + 0] = q.x ? v.x : v.x + NEGC;
    x[j * 4 + 1] = q.y ? v.y : v.y + NEGC;
    x[j * 4 + 2] = q.z ? v.z : v.z + NEGC;
    x[j * 4 + 3] = q.w ? v.w : v.w + NEGC;
  }
  float mx = x[0];
#pragma unroll
  for (int j = 1; j < 32; ++j) mx = fmaxf(mx, x[j]);
#pragma unroll
  for (int o = 32; o >= 1; o >>= 1) mx = fmaxf(mx, __shfl_xor(mx, o, 64));
  float sum = 0.f;
#pragma unroll
  for (int j = 0; j < 32; ++j) { x[j] = __expf(x[j] - mx); sum += x[j]; }
#pragma unroll
  for (int o = 32; o >= 1; o >>= 1) sum += __shfl_xor(sum, o, 64);
  float inv = 1.f / sum;
#pragma unroll
  for (int j = 0; j < 8; ++j) {
    ushort4 o4 = make_ushort4(f2h(x[j * 4 + 0] * inv), f2h(x[j * 4 + 1] * inv),
                              f2h(x[j * 4 + 2] * inv), f2h(x[j * 4 + 3] * inv));
    *(ushort4*)(p + lane * 4 + j * 256) = o4;
  }
}

extern "C" void kernel_launch(void* const* d_in, const int* in_sizes, int n_in,
                              void* d_out, int out_size, void* d_ws, size_t ws_size,
                              hipStream_t stream) {
  const float* query = (const float*)d_in[0];
  const float* mem = (const float*)d_in[1];
  const int* mask = (const int*)d_in[2];
  const float* Wm = (const float*)d_in[3];
  const float* bias = (const float*)d_in[4];
  float* out = (float*)d_out;   // fp32 output

  const long nQ = (long)B_ * SQL * DD;   // 16.7M
  const long nW = (long)DD * DD;
  const long nS = (long)B_ * SQL * SKL;

  char* ws = (char*)d_ws;
  u16* q16 = (u16*)ws; ws += nQ * 2;    // fp16(query); becomes P after proj+QK
  u16* memh = (u16*)ws; ws += nQ * 2;
  u16* memT = (u16*)ws; ws += nQ * 2;
  u16* q1 = (u16*)ws; ws += nQ * 2;     // projected q, fp16
  u16* wh = (u16*)ws; ws += nW * 2;
  u16* wl = (u16*)ws; ws += nW * 2;
  float* S = (float*)ws; ws += nS * 4;
  u16* P = q16;   // q16 dead after projection

  cvt16_k<<<2048, 256, 0, stream>>>(query, q16, nQ);
  split16_k<<<512, 256, 0, stream>>>(Wm, wh, wl, nW);
  split_mem16_k<<<dim3(DD / 64, SKL / 64, B_), 256, 0, stream>>>(mem, memh, memT);

  // projection (2-term, 256x128): M=16384, N=D, K=D ; q -> fp16
  gemm_f16<2, 1, true><<<dim3(DD / 128, (B_ * SQL) / 256, 1), 256, 0, stream>>>(
      q16, wh, wl, bias, q1, DD, DD, 0, 0, 0);
  // logits (1-term, 256x128): per batch M=Sq, N=Sk, K=D ; fp32 S
  gemm_f16<1, 0, false><<<dim3(SKL / 128, SQL / 256, B_), 256, 0, stream>>>(
      q1, memh, nullptr, nullptr, S, SKL, DD,
      (long)SQL * DD, (long)SKL * DD, (long)SQL * SKL);
  // mask + softmax -> P fp16 (wave-per-row)
  softmax16_k<<<(B_ * SQL) / 4, 256, 0, stream>>>(S, mask, P);
  // PV (1-term, 256x128): per batch M=Sq, N=D, K=Sk ; B = memT ; fp32 out
  gemm_f16<1, 0, false><<<dim3(DD / 128, SQL / 256, B_), 256, 0, stream>>>(
      P, memT, nullptr, nullptr, out, DD, SKL,
      (long)SQL * SKL, (long)DD * SKL, (long)SQL * DD);
}

// Round 21
// 317.391 us; speedup vs baseline: 1.1424x; 1.0132x over previous
//
#include <hip/hip_runtime.h>

// Round 21: batch-folded 1-D grid + whole-grid bijective XCD swizzle on all
// GEMMs. R20 diagnosis: QK/PV fetch 2.2-2.4x ideal because z-dim batch
// dispatch mixes batches on each XCD's L2. Folding (bz,by,bx) into one grid
// with chunked swizzle gives each XCD exactly ONE batch (QK: 1024/8=128 =
// one batch's tiles). Pure index permutation; everything else = R20 (321.6us).

typedef __attribute__((ext_vector_type(8))) _Float16 f16x8;
typedef __attribute__((ext_vector_type(4))) float f32x4;
typedef unsigned short u16;
typedef unsigned int u32;

#define B_ 8
#define SQL 2048
#define SKL 2048
#define DD 1024
#define NEGC -1000000000.0f

static __device__ __forceinline__ u16 f2h(float x) {
  _Float16 h = (_Float16)x;                       // v_cvt_f16_f32, RNE
  return __builtin_bit_cast(u16, h);
}
static __device__ __forceinline__ float h2f(u16 v) {
  return (float)__builtin_bit_cast(_Float16, v);
}
static __device__ __forceinline__ void gload16(const void* g, void* l) {
  __builtin_amdgcn_global_load_lds((const __attribute__((address_space(1))) u32*)g,
                                   (__attribute__((address_space(3))) u32*)l, 16, 0, 0);
}

// ---------------- convert fp32 -> fp16 (single) ----------------
__global__ __launch_bounds__(256) void cvt16_k(const float* __restrict__ in,
                                               u16* __restrict__ out, long n) {
  long i = ((long)blockIdx.x * 256 + threadIdx.x) * 8;
  long stride = (long)gridDim.x * 256 * 8;
  for (; i < n; i += stride) {
    float4 v0 = *(const float4*)(in + i);
    float4 v1 = *(const float4*)(in + i + 4);
    ushort4 o0 = make_ushort4(f2h(v0.x), f2h(v0.y), f2h(v0.z), f2h(v0.w));
    ushort4 o1 = make_ushort4(f2h(v1.x), f2h(v1.y), f2h(v1.z), f2h(v1.w));
    *(ushort4*)(out + i) = o0;
    *(ushort4*)(out + i + 4) = o1;
  }
}

// ---------------- split fp32 -> fp16 hi + fp16 lo (for W) ----------------
__global__ __launch_bounds__(256) void split16_k(const float* __restrict__ in,
                                                 u16* __restrict__ hi, u16* __restrict__ lo,
                                                 long n) {
  long i = ((long)blockIdx.x * 256 + threadIdx.x) * 4;
  long stride = (long)gridDim.x * 256 * 4;
  for (; i < n; i += stride) {
    float4 v = *(const float4*)(in + i);
    u16 h0 = f2h(v.x), h1 = f2h(v.y), h2 = f2h(v.z), h3 = f2h(v.w);
    *(ushort4*)(hi + i) = make_ushort4(h0, h1, h2, h3);
    *(ushort4*)(lo + i) = make_ushort4(f2h(v.x - h2f(h0)), f2h(v.y - h2f(h1)),
                                       f2h(v.z - h2f(h2)), f2h(v.w - h2f(h3)));
  }
}

// ---------------- fused mem: fp32 [Sk][D] -> memh fp16 + memT fp16 [D][Sk] ----------------
__global__ __launch_bounds__(256) void split_mem16_k(const float* __restrict__ in,
                                                     u16* __restrict__ hi,
                                                     u16* __restrict__ trn) {
  __shared__ u16 t[64][65];
  long bo = (long)blockIdx.z * SKL * DD;
  int r0 = blockIdx.y * 64, c0 = blockIdx.x * 64;
  int tr = threadIdx.x / 16, tc4 = (threadIdx.x % 16) * 4;
#pragma unroll
  for (int i = 0; i < 4; ++i) {
    int r = tr + i * 16;
    long idx = bo + (long)(r0 + r) * DD + c0 + tc4;
    float4 v = *(const float4*)(in + idx);
    u16 h0 = f2h(v.x), h1 = f2h(v.y), h2 = f2h(v.z), h3 = f2h(v.w);
    *(ushort4*)(hi + idx) = make_ushort4(h0, h1, h2, h3);
    t[r][tc4 + 0] = h0; t[r][tc4 + 1] = h1; t[r][tc4 + 2] = h2; t[r][tc4 + 3] = h3;
  }
  __syncthreads();
#pragma unroll
  for (int i = 0; i < 4; ++i) {
    int c = tr + i * 16;   // output row = original column c0+c
    ushort4 v = make_ushort4(t[tc4 + 0][c], t[tc4 + 1][c], t[tc4 + 2][c], t[tc4 + 3][c]);
    *(ushort4*)(trn + bo + (long)(c0 + c) * SKL + r0 + tc4) = v;
  }
}

// ---------------- unified B^T-layout fp16 MFMA GEMM ----------------
// C[m][n] = sum_k A[m][k]*B[n][k]; 256x128 tile, 4 waves (2x2), BK=64,
// single-buffer LDS, mfma_f32_16x16x32_f16, XOR-swizzled via pre-swizzled
// global source. 1-D batch-folded grid: id -> XCD-chunked j -> (bz,by,bx);
// each XCD owns a contiguous span (= one batch for QK/PV).
// TERMS=2: B dual (Bh|Bl) 16-chunk 256B rows.  proj
// TERMS=1: B single 8-chunk rows.              QK/PV
// OUTMODE: 0 = fp32 ; 1 = fp16 single
template <int TERMS, int OUTMODE, bool BIAS>
__global__ __launch_bounds__(256, 2) void gemm_f16(
    const u16* __restrict__ Ah,
    const u16* __restrict__ Bh, const u16* __restrict__ Bl,
    const float* __restrict__ bias,
    void* __restrict__ C0,
    int N, int K, int TPB,   // TPB = tiles per batch (TY*TX)
    long batchA, long batchB, long batchC) {
  constexpr int BM = 256;
  constexpr int MF = 8;                          // M fragments per wave
  constexpr int RWB = (TERMS == 2) ? 128 : 64;   // u16 per B LDS row
  __shared__ u16 lA[BM * 64];
  __shared__ u16 lB[128 * RWB];

  // ---- batch-folded bijective XCD swizzle (gridDim.x % 8 == 0) ----
  const int nwg = gridDim.x;
  int id = blockIdx.x;
  int j = (id & 7) * (nwg >> 3) + (id >> 3);
  const int TX = N >> 7;                  // N/128
  const int bz = j / TPB;
  const int r0_ = j % TPB;
  const int by = r0_ / TX, bx = r0_ % TX;

  const u16* pAh = Ah + (long)bz * batchA;
  const u16* pBh = Bh + (long)bz * batchB;
  const u16* pBl = (TERMS == 2) ? Bl : nullptr;   // proj W has no batch

  const int tid = threadIdx.x;
  const int l = tid & 63, w = tid >> 6;
  const int wr = w >> 1, wc = w & 1;
  const long am0 = (long)by * BM;
  const long bn0 = (long)bx * 128;

  f32x4 acc[MF][4];
#pragma unroll
  for (int i = 0; i < MF; ++i)
#pragma unroll
    for (int j2 = 0; j2 < 4; ++j2) {
      f32x4 z = {0.f, 0.f, 0.f, 0.f};
      acc[i][j2] = z;
    }

  const int lrow = l & 15, lch = l >> 4;

  for (int k0 = 0; k0 < K; k0 += 64) {
    __syncthreads();
    // ---- A stage: single fp16, 8 chunks/row (proven involution) ----
#pragma unroll
    for (int i = 0; i < BM / 32; ++i) {
      int row = i * 32 + (tid >> 3);
      int cc = (tid & 7) ^ (row & 7);
      gload16(pAh + (am0 + row) * K + k0 + cc * 8, &lA[row * 64 + (tid & 7) * 8]);
    }
    // ---- B stage ----
    if (TERMS == 2) {
#pragma unroll
      for (int i = 0; i < 8; ++i) {
        int row = i * 16 + (tid >> 4);
        int s = tid & 15;
        int cc = s ^ (row & 15);
        const u16* src = (cc < 8) ? (pBh + (bn0 + row) * K + k0 + cc * 8)
                                  : (pBl + (bn0 + row) * K + k0 + (cc - 8) * 8);
        gload16(src, &lB[row * 128 + s * 8]);
      }
    } else {
#pragma unroll
      for (int i = 0; i < 4; ++i) {
        int row = i * 32 + (tid >> 3);
        int cc = (tid & 7) ^ (row & 7);
        gload16(pBh + (bn0 + row) * K + k0 + cc * 8, &lB[row * 64 + (tid & 7) * 8]);
      }
    }
    __syncthreads();

#pragma unroll
    for (int kk = 0; kk < 2; ++kk) {
      if (TERMS == 2) {
        f16x8 ah[8], bh[4], bl_[4];
#pragma unroll
        for (int f = 0; f < 8; ++f) {
          int ra = wr * 128 + f * 16 + lrow;
          int c = kk * 4 + lch;
          ah[f] = *(const f16x8*)&lA[ra * 64 + (c ^ (ra & 7)) * 8];
        }
#pragma unroll
        for (int f = 0; f < 4; ++f) {
          int rb = wc * 64 + f * 16 + lrow;
          int c = kk * 4 + lch;
          bh[f] = *(const f16x8*)&lB[rb * 128 + (c ^ (rb & 15)) * 8];
          bl_[f] = *(const f16x8*)&lB[rb * 128 + ((8 + c) ^ (rb & 15)) * 8];
        }
#pragma unroll
        for (int mf = 0; mf < 8; ++mf)
#pragma unroll
          for (int nf = 0; nf < 4; ++nf) {
            acc[mf][nf] = __builtin_amdgcn_mfma_f32_16x16x32_f16(ah[mf], bh[nf], acc[mf][nf], 0, 0, 0);
            acc[mf][nf] = __builtin_amdgcn_mfma_f32_16x16x32_f16(ah[mf], bl_[nf], acc[mf][nf], 0, 0, 0);
          }
      } else {
        f16x8 ah[8], bh[4];
#pragma unroll
        for (int f = 0; f < 8; ++f) {
          int ra = wr * 128 + f * 16 + lrow;
          int c = kk * 4 + lch;
          ah[f] = *(const f16x8*)&lA[ra * 64 + (c ^ (ra & 7)) * 8];
        }
#pragma unroll
        for (int f = 0; f < 4; ++f) {
          int rb = wc * 64 + f * 16 + lrow;
          int c = kk * 4 + lch;
          bh[f] = *(const f16x8*)&lB[rb * 64 + (c ^ (rb & 7)) * 8];
        }
#pragma unroll
        for (int mf = 0; mf < 8; ++mf)
#pragma unroll
          for (int nf = 0; nf < 4; ++nf)
            acc[mf][nf] = __builtin_amdgcn_mfma_f32_16x16x32_f16(ah[mf], bh[nf], acc[mf][nf], 0, 0, 0);
      }
    }
  }

  // epilogue: C/D layout col = lane&15, row = (lane>>4)*4 + reg
#pragma unroll
  for (int mf = 0; mf < MF; ++mf)
#pragma unroll
    for (int nf = 0; nf < 4; ++nf)
#pragma unroll
      for (int r = 0; r < 4; ++r) {
        long row = am0 + wr * 128 + mf * 16 + (l >> 4) * 4 + r;
        long col = bn0 + wc * 64 + nf * 16 + (l & 15);
        float v = acc[mf][nf][r];
        if (BIAS) v += bias[col];
        long idx = (long)bz * batchC + row * N + col;
        if (OUTMODE == 0) ((float*)C0)[idx] = v;
        else              ((u16*)C0)[idx] = f2h(v);
      }
}

// ---------------- mask + row softmax, wave-per-row (no barriers/LDS) ----------------
__global__ __launch_bounds__(256) void softmax16_k(const float* __restrict__ S,
                                                   const int* __restrict__ M,
                                                   u16* __restrict__ P) {
  long row = (long)blockIdx.x * 4 + (threadIdx.x >> 6);
  const float* s = S + row * SKL;
  const int* m = M + row * SKL;
  u16* p = P + row * SKL;
  const int lane = threadIdx.x & 63;
  float x[32];
#pragma unroll
  for (int j = 0; j < 8; ++j) {
    float4 v = *(const float4*)(s + lane * 4 + j * 256);
    int4 q = *(const int4*)(m + lane * 4 + j * 256);
    x[j * 4 + 0] = q.x ? v.x : v.x + NEGC;
    x[j * 4 + 1] = q.y ? v.y : v.y + NEGC;
    x[j * 4 + 2] = q.z ? v.z : v.z + NEGC;
    x[j * 4 + 3] = q.w ? v.w : v.w + NEGC;
  }
  float mx = x[0];
#pragma unroll
  for (int j = 1; j < 32; ++j) mx = fmaxf(mx, x[j]);
#pragma unroll
  for (int o = 32; o >= 1; o >>= 1) mx = fmaxf(mx, __shfl_xor(mx, o, 64));
  float sum = 0.f;
#pragma unroll
  for (int j = 0; j < 32; ++j) { x[j] = __expf(x[j] - mx); sum += x[j]; }
#pragma unroll
  for (int o = 32; o >= 1; o >>= 1) sum += __shfl_xor(sum, o, 64);
  float inv = 1.f / sum;
#pragma unroll
  for (int j = 0; j < 8; ++j) {
    ushort4 o4 = make_ushort4(f2h(x[j * 4 + 0] * inv), f2h(x[j * 4 + 1] * inv),
                              f2h(x[j * 4 + 2] * inv), f2h(x[j * 4 + 3] * inv));
    *(ushort4*)(p + lane * 4 + j * 256) = o4;
  }
}

extern "C" void kernel_launch(void* const* d_in, const int* in_sizes, int n_in,
                              void* d_out, int out_size, void* d_ws, size_t ws_size,
                              hipStream_t stream) {
  const float* query = (const float*)d_in[0];
  const float* mem = (const float*)d_in[1];
  const int* mask = (const int*)d_in[2];
  const float* Wm = (const float*)d_in[3];
  const float* bias = (const float*)d_in[4];
  float* out = (float*)d_out;   // fp32 output

  const long nQ = (long)B_ * SQL * DD;   // 16.7M
  const long nW = (long)DD * DD;
  const long nS = (long)B_ * SQL * SKL;

  char* ws = (char*)d_ws;
  u16* q16 = (u16*)ws; ws += nQ * 2;    // fp16(query); becomes P after proj+QK
  u16* memh = (u16*)ws; ws += nQ * 2;
  u16* memT = (u16*)ws; ws += nQ * 2;
  u16* q1 = (u16*)ws; ws += nQ * 2;     // projected q, fp16
  u16* wh = (u16*)ws; ws += nW * 2;
  u16* wl = (u16*)ws; ws += nW * 2;
  float* S = (float*)ws; ws += nS * 4;
  u16* P = q16;   // q16 dead after projection

  cvt16_k<<<2048, 256, 0, stream>>>(query, q16, nQ);
  split16_k<<<512, 256, 0, stream>>>(Wm, wh, wl, nW);
  split_mem16_k<<<dim3(DD / 64, SKL / 64, B_), 256, 0, stream>>>(mem, memh, memT);

  // projection (2-term, 256x128): M=16384, N=D, K=D ; q -> fp16
  // grid = 1 batch x TY=64 x TX=8 = 512
  gemm_f16<2, 1, true><<<512, 256, 0, stream>>>(
      q16, wh, wl, bias, q1, DD, DD, 512, 0, 0, 0);
  // logits (1-term, 256x128): per batch M=Sq, N=Sk ; grid = 8 x 8 x 16 = 1024
  gemm_f16<1, 0, false><<<1024, 256, 0, stream>>>(
      q1, memh, nullptr, nullptr, S, SKL, DD, 128,
      (long)SQL * DD, (long)SKL * DD, (long)SQL * SKL);
  // mask + softmax -> P fp16 (wave-per-row)
  softmax16_k<<<(B_ * SQL) / 4, 256, 0, stream>>>(S, mask, P);
  // PV (1-term, 256x128): per batch M=Sq, N=D ; grid = 8 x 8 x 8 = 512
  gemm_f16<1, 0, false><<<512, 256, 0, stream>>>(
      P, memT, nullptr, nullptr, out, DD, SKL, 64,
      (long)SQL * SKL, (long)DD * SKL, (long)SQL * DD);
}